// Round 1
// baseline (145.523 us; speedup 1.0000x reference)
//
#include <hip/hip_runtime.h>
#include <math.h>

namespace {

constexpr int kB = 4;
constexpr int kS = 4;
constexpr int kM = 1024;
constexpr int kN = 8192;
constexpr float kBig2 = 1e20f;  // sqrt(1e20) = 1e10 == reference BIG

constexpr int K1_NSPLIT = 8;   // split N range across blocks, atomicMin combine
constexpr int K2_MSPLIT = 2;   // split M range across blocks, atomicMin combine

__global__ __launch_bounds__(256) void init_ws_k(unsigned int* w, int n) {
  int i = blockIdx.x * 256 + threadIdx.x;
  if (i < n) w[i] = __float_as_uint(kBig2);
}

// d1 direction: for each (b,s,m), min over n with lab==s of squared distance.
__global__ __launch_bounds__(256) void k1_pred_to_gt(
    const float* __restrict__ ret, const float4* __restrict__ gt,
    unsigned int* __restrict__ d1minsq) {
  constexpr int NCH = kN / K1_NSPLIT;  // 1024
  int blk = blockIdx.x;
  const int nsp = blk % K1_NSPLIT; blk /= K1_NSPLIT;
  const int mch = blk % (kM / 256); blk /= (kM / 256);
  const int s = blk % kS;
  const int b = blk / kS;
  const int m = mch * 256 + threadIdx.x;
  const float* p = ret + (((b * kS + s) * kM) + m) * 3;
  const float px = p[0], py = p[1], pz = p[2];
  const float sf = (float)s;
  float best = kBig2;
  __shared__ float4 g[256];
  for (int n0 = nsp * NCH; n0 < nsp * NCH + NCH; n0 += 256) {
    __syncthreads();
    float4 q = gt[b * kN + n0 + threadIdx.x];
    // Fold the label mask into an additive bias: matching -> +0, else -> +BIG2.
    q.w = (q.w == sf) ? 0.0f : kBig2;
    g[threadIdx.x] = q;
    __syncthreads();
#pragma unroll 8
    for (int j = 0; j < 256; ++j) {
      float4 t = g[j];  // wave-uniform address -> LDS broadcast, conflict-free
      float dx = px - t.x, dy = py - t.y, dz = pz - t.z;
      float d2 = fmaf(dx, dx, fmaf(dy, dy, dz * dz)) + t.w;
      best = fminf(best, d2);
    }
  }
  // d2 >= 0 so float bits are monotone as uint -> atomicMin on bits is valid.
  atomicMin(&d1minsq[(b * kS + s) * kM + m], __float_as_uint(best));
}

// d2m direction: for each (b,n), min over m of squared dist to pred[b, lab(n), m].
__global__ __launch_bounds__(256) void k2_gt_to_pred(
    const float* __restrict__ ret, const float4* __restrict__ gt,
    unsigned int* __restrict__ dminsq) {
  constexpr int MCH = kM / K2_MSPLIT;  // 512
  constexpr int TILE = 128;
  int blk = blockIdx.x;
  const int msp = blk % K2_MSPLIT; blk /= K2_MSPLIT;
  const int nch = blk % (kN / 256);
  const int b = blk / (kN / 256);
  const int n = nch * 256 + threadIdx.x;
  const float4 q = gt[b * kN + n];
  const int s = (int)q.w;
  const float* base = ret + b * kS * kM * 3;
  float best = kBig2;
  // +4 pad -> per-label stride 388 % 32 = 4 banks apart: no 4-way conflicts.
  __shared__ float pl[kS][TILE * 3 + 4];
  for (int m0 = msp * MCH; m0 < msp * MCH + MCH; m0 += TILE) {
    __syncthreads();
    for (int t = threadIdx.x; t < kS * TILE * 3; t += 256) {
      int ss = t / (TILE * 3);
      int r = t - ss * (TILE * 3);
      pl[ss][r] = base[ss * kM * 3 + m0 * 3 + r];
    }
    __syncthreads();
#pragma unroll 4
    for (int mm = 0; mm < TILE; ++mm) {
      float gx = pl[s][mm * 3 + 0];
      float gy = pl[s][mm * 3 + 1];
      float gz = pl[s][mm * 3 + 2];
      float dx = q.x - gx, dy = q.y - gy, dz = q.z - gz;
      float d2 = fmaf(dx, dx, fmaf(dy, dy, dz * dz));
      best = fminf(best, d2);
    }
  }
  atomicMin(&dminsq[b * kN + n], __float_as_uint(best));
}

// Per-(b,s) reduction: d1 mean over m, masked sum of dmin over n, cnt.
__global__ __launch_bounds__(256) void k3_reduce_bs(
    const unsigned int* __restrict__ d1minsq,
    const unsigned int* __restrict__ dminsq,
    const float4* __restrict__ gt,
    float* __restrict__ chamfer, int* __restrict__ cnt) {
  const int s = blockIdx.x % kS;
  const int b = blockIdx.x / kS;
  float s1 = 0.f;
  for (int m = threadIdx.x; m < kM; m += 256) {
    s1 += sqrtf(fmaxf(__uint_as_float(d1minsq[(b * kS + s) * kM + m]), 1e-12f));
  }
  float s2 = 0.f;
  int c = 0;
  for (int n = threadIdx.x; n < kN; n += 256) {
    float4 q = gt[b * kN + n];
    if ((int)q.w == s) {
      c += 1;
      s2 += sqrtf(fmaxf(__uint_as_float(dminsq[b * kN + n]), 1e-12f));
    }
  }
  for (int off = 32; off > 0; off >>= 1) {
    s1 += __shfl_down(s1, off);
    s2 += __shfl_down(s2, off);
    c += __shfl_down(c, off);
  }
  __shared__ float r1[4], r2[4];
  __shared__ int rc[4];
  const int wid = threadIdx.x >> 6;
  if ((threadIdx.x & 63) == 0) { r1[wid] = s1; r2[wid] = s2; rc[wid] = c; }
  __syncthreads();
  if (threadIdx.x == 0) {
    float a1 = 0.f, a2 = 0.f;
    int ac = 0;
    for (int w = 0; w < 4; ++w) { a1 += r1[w]; a2 += r2[w]; ac += rc[w]; }
    float d1 = a1 / (float)kM;
    float d2m = a2 / (float)max(ac, 1);
    float ch = 0.5f * (d1 + d2m);
    chamfer[b * kS + s] = (ac > 0) ? ch : 0.f;  // where(present, chamfer, 0)
    cnt[b * kS + s] = ac;
  }
}

__global__ void k4_final(const float* __restrict__ chamfer,
                         const int* __restrict__ cnt,
                         float* __restrict__ out) {
  if (threadIdx.x == 0 && blockIdx.x == 0) {
    float acc = 0.f;
    for (int b = 0; b < kB; ++b) {
      float sum = 0.f;
      int pres = 0;
      for (int s = 0; s < kS; ++s) {
        sum += chamfer[b * kS + s];
        if (cnt[b * kS + s] > 0) pres += 1;
      }
      acc += sum / (float)max(pres, 1);
    }
    out[0] = acc / (float)kB;
  }
}

}  // namespace

extern "C" void kernel_launch(void* const* d_in, const int* in_sizes, int n_in,
                              void* d_out, int out_size, void* d_ws, size_t ws_size,
                              hipStream_t stream) {
  const float* ret = (const float*)d_in[0];     // (B, S*M*3) f32
  const float4* gt = (const float4*)d_in[1];    // (B, N, 4) f32 -> float4
  unsigned int* d1minsq = (unsigned int*)d_ws;            // B*S*M
  unsigned int* dminsq = d1minsq + kB * kS * kM;          // B*N
  float* chamfer = (float*)(dminsq + kB * kN);            // B*S
  int* cnt = (int*)(chamfer + kB * kS);                   // B*S

  const int initN = kB * kS * kM + kB * kN;
  init_ws_k<<<(initN + 255) / 256, 256, 0, stream>>>((unsigned int*)d_ws, initN);
  k1_pred_to_gt<<<kB * kS * (kM / 256) * K1_NSPLIT, 256, 0, stream>>>(ret, gt, d1minsq);
  k2_gt_to_pred<<<kB * (kN / 256) * K2_MSPLIT, 256, 0, stream>>>(ret, gt, dminsq);
  k3_reduce_bs<<<kB * kS, 256, 0, stream>>>(d1minsq, dminsq, gt, chamfer, cnt);
  k4_final<<<1, 64, 0, stream>>>(chamfer, cnt, (float*)d_out);
}

// Round 2
// 124.524 us; speedup vs baseline: 1.1686x; 1.1686x over previous
//
#include <hip/hip_runtime.h>
#include <math.h>

namespace {

constexpr int kB = 4;
constexpr int kS = 4;
constexpr int kM = 1024;
constexpr int kN = 8192;
constexpr int kBS = kB * kS;
constexpr float kBig2 = 1e20f;  // sqrt(1e20) = 1e10 == reference BIG

// ---- workspace layout (4-byte units) ----
constexpr int OFF_D1 = 0;                       // B*S*M  per-(b,s,m) min d2 bits
constexpr int OFF_DM = OFF_D1 + kBS * kM;       // B*N    per-compacted-gt min d2 bits
constexpr int OFF_CX = OFF_DM + kB * kN;        // B*N floats (compacted SoA)
constexpr int OFF_CY = OFF_CX + kB * kN;
constexpr int OFF_CZ = OFF_CY + kB * kN;
constexpr int NCB = (kB * kN) / 256;            // 128 count blocks
constexpr int OFF_BH = OFF_CZ + kB * kN;        // block histograms NCB*kS
constexpr int OFF_CNT = OFF_BH + NCB * kS;      // 16 counts
constexpr int OFF_OFS = OFF_CNT + kBS;          // 16 absolute bucket offsets
constexpr int OFF_CUR = OFF_OFS + kBS;          // 16 scatter cursors

constexpr int INIT_BLOCKS = (kBS * kM + kB * kN) / 256;  // 192 (d1 + dm contiguous)

constexpr int NSPL1 = 16;      // k1-role: split of bucket tiles
constexpr int K1_TILE = 128;
constexpr int K1_BLOCKS = kBS * NSPL1;          // 256
constexpr int GSPL = 4;        // k2-role: split over bucket points
constexpr int MSPL = 8;        // k2-role: split over M (tiles of 128)
constexpr int K2_BLOCKS = kBS * GSPL * MSPL;    // 512

// init d1/dm mins to BIG2 bits; per-block label histograms (no pre-zero needed).
__global__ __launch_bounds__(256) void kprep(const float* __restrict__ gtf,
                                             unsigned int* __restrict__ ws) {
  const int blk = blockIdx.x, tid = threadIdx.x;
  if (blk < INIT_BLOCKS) {
    ws[blk * 256 + tid] = __float_as_uint(kBig2);
  } else {
    const int cb = blk - INIT_BLOCKS;          // 256 points per block, single b
    const int idx = cb * 256 + tid;
    const int s = (int)gtf[idx * 4 + 3];
    __shared__ int h[kS];
    if (tid < kS) h[tid] = 0;
    __syncthreads();
    atomicAdd(&h[s], 1);
    __syncthreads();
    if (tid < kS) ((int*)ws)[OFF_BH + cb * kS + tid] = h[tid];
  }
}

// sum histograms -> counts; exclusive prefix per b -> offsets (+cursor copy).
__global__ void koffsets(unsigned int* ws) {
  const int t = threadIdx.x;  // 64 threads
  __shared__ int c[kBS];
  int* wi = (int*)ws;
  if (t < kBS) {
    const int b = t / kS, s = t % kS;
    int sum = 0;
    for (int j = 0; j < NCB / kB; ++j) sum += wi[OFF_BH + (b * (NCB / kB) + j) * kS + s];
    c[t] = sum;
    wi[OFF_CNT + t] = sum;
  }
  __syncthreads();
  if (t < kB) {
    int base = t * kN;
    for (int s = 0; s < kS; ++s) {
      wi[OFF_OFS + t * kS + s] = base;
      wi[OFF_CUR + t * kS + s] = base;
      base += c[t * kS + s];
    }
  }
}

// scatter gt into per-(b,s) buckets (SoA) with wave-aggregated cursor allocs.
__global__ __launch_bounds__(256) void kscatter(const float4* __restrict__ gt,
                                                unsigned int* __restrict__ ws) {
  const int idx = blockIdx.x * 256 + threadIdx.x;  // single b per block
  const int b = idx >> 13;
  const int lane = threadIdx.x & 63;
  const float4 q = gt[idx];
  const int s = (int)q.w;
  int* wi = (int*)ws;
  int pos = 0;
  for (int ss = 0; ss < kS; ++ss) {
    unsigned long long m = __ballot(s == ss);
    if (m != 0ull) {
      const int leader = __ffsll((unsigned long long)m) - 1;
      int base = 0;
      if (lane == leader) base = atomicAdd(&wi[OFF_CUR + b * kS + ss], (int)__popcll(m));
      base = __shfl(base, leader);
      if (s == ss) pos = base + (int)__popcll(m & ((1ull << lane) - 1ull));
    }
  }
  float* cx = (float*)(ws + OFF_CX);
  float* cy = (float*)(ws + OFF_CY);
  float* cz = (float*)(ws + OFF_CZ);
  cx[pos] = q.x;
  cy[pos] = q.y;
  cz[pos] = q.z;
}

// merged distance kernel: blocks [0,K1_BLOCKS) do pred->gt row mins,
// blocks [K1_BLOCKS, +K2_BLOCKS) do gt->pred col mins. All per-(b,s) bucket.
__global__ __launch_bounds__(256) void kdist(const float* __restrict__ ret,
                                             unsigned int* __restrict__ ws) {
  const int tid = threadIdx.x;
  __shared__ float4 tile4[K1_TILE];
  const int* wi = (const int*)ws;
  const float* cx = (const float*)(ws + OFF_CX);
  const float* cy = (const float*)(ws + OFF_CY);
  const float* cz = (const float*)(ws + OFF_CZ);

  if (blockIdx.x < K1_BLOCKS) {
    // ---- k1 role: 256 threads x 4 pred points = full M; loop bucket tiles ----
    const int nsp = blockIdx.x % NSPL1;
    const int bs = blockIdx.x / NSPL1;
    const int off = wi[OFF_OFS + bs];
    const int cnt = wi[OFF_CNT + bs];
    const float* p = ret + (bs * kM + tid) * 3;
    const float px0 = p[0], py0 = p[1], pz0 = p[2];
    const float px1 = p[768], py1 = p[769], pz1 = p[770];
    const float px2 = p[1536], py2 = p[1537], pz2 = p[1538];
    const float px3 = p[2304], py3 = p[2305], pz3 = p[2306];
    float b0 = kBig2, b1 = kBig2, b2 = kBig2, b3 = kBig2;
    for (int t = nsp; t * K1_TILE < cnt; t += NSPL1) {
      const int start = t * K1_TILE;
      __syncthreads();
      if (tid < K1_TILE) {
        const int j = start + tid;
        float4 v;
        if (j < cnt) { v.x = cx[off + j]; v.y = cy[off + j]; v.z = cz[off + j]; }
        else { v.x = 1e15f; v.y = 1e15f; v.z = 1e15f; }  // pad: never wins the min
        v.w = 0.f;
        tile4[tid] = v;
      }
      __syncthreads();
#pragma unroll 8
      for (int j = 0; j < K1_TILE; ++j) {
        const float4 tv = tile4[j];  // wave-uniform -> LDS broadcast
        float dx, dy, dz;
        dx = px0 - tv.x; dy = py0 - tv.y; dz = pz0 - tv.z;
        b0 = fminf(b0, fmaf(dx, dx, fmaf(dy, dy, dz * dz)));
        dx = px1 - tv.x; dy = py1 - tv.y; dz = pz1 - tv.z;
        b1 = fminf(b1, fmaf(dx, dx, fmaf(dy, dy, dz * dz)));
        dx = px2 - tv.x; dy = py2 - tv.y; dz = pz2 - tv.z;
        b2 = fminf(b2, fmaf(dx, dx, fmaf(dy, dy, dz * dz)));
        dx = px3 - tv.x; dy = py3 - tv.y; dz = pz3 - tv.z;
        b3 = fminf(b3, fmaf(dx, dx, fmaf(dy, dy, dz * dz)));
      }
    }
    atomicMin(&ws[OFF_D1 + bs * kM + tid], __float_as_uint(b0));
    atomicMin(&ws[OFF_D1 + bs * kM + tid + 256], __float_as_uint(b1));
    atomicMin(&ws[OFF_D1 + bs * kM + tid + 512], __float_as_uint(b2));
    atomicMin(&ws[OFF_D1 + bs * kM + tid + 768], __float_as_uint(b3));
  } else {
    // ---- k2 role: 256 threads x 2 gt points; loop 128-pred LDS tile ----
    int blk2 = blockIdx.x - K1_BLOCKS;
    const int ms = blk2 & (MSPL - 1); blk2 >>= 3;
    const int gs = blk2 & (GSPL - 1); blk2 >>= 2;
    const int bs = blk2;
    const int off = wi[OFF_OFS + bs];
    const int cnt = wi[OFF_CNT + bs];
    if (tid < 128) {
      const float* bp = ret + (bs * kM + ms * 128 + tid) * 3;
      tile4[tid] = make_float4(bp[0], bp[1], bp[2], 0.f);
    }
    __syncthreads();
    for (int base0 = gs * 512; base0 < cnt; base0 += GSPL * 512) {
      const int l0 = base0 + tid, l1 = base0 + 256 + tid;
      const bool v0 = l0 < cnt, v1 = l1 < cnt;
      const float gx0 = v0 ? cx[off + l0] : 0.f;
      const float gy0 = v0 ? cy[off + l0] : 0.f;
      const float gz0 = v0 ? cz[off + l0] : 0.f;
      const float gx1 = v1 ? cx[off + l1] : 0.f;
      const float gy1 = v1 ? cy[off + l1] : 0.f;
      const float gz1 = v1 ? cz[off + l1] : 0.f;
      float b0 = kBig2, b1 = kBig2;
#pragma unroll 8
      for (int mm = 0; mm < 128; ++mm) {
        const float4 pv = tile4[mm];  // wave-uniform broadcast
        float dx, dy, dz;
        dx = gx0 - pv.x; dy = gy0 - pv.y; dz = gz0 - pv.z;
        b0 = fminf(b0, fmaf(dx, dx, fmaf(dy, dy, dz * dz)));
        dx = gx1 - pv.x; dy = gy1 - pv.y; dz = gz1 - pv.z;
        b1 = fminf(b1, fmaf(dx, dx, fmaf(dy, dy, dz * dz)));
      }
      if (v0) atomicMin(&ws[OFF_DM + off + l0], __float_as_uint(b0));
      if (v1) atomicMin(&ws[OFF_DM + off + l1], __float_as_uint(b1));
    }
  }
}

// single-block final: sqrt+mean both directions per (b,s), chamfer, batch mean.
__global__ __launch_bounds__(256) void kfinal(const unsigned int* __restrict__ ws,
                                              float* __restrict__ out) {
  const int tid = threadIdx.x, lane = tid & 63, wid = tid >> 6;
  __shared__ float r1[4], r2[4];
  __shared__ float cham[kBS];
  __shared__ int pres[kBS];
  const int* wi = (const int*)ws;
  for (int bs = 0; bs < kBS; ++bs) {
    const int cnt = wi[OFF_CNT + bs];
    const int off = wi[OFF_OFS + bs];
    float s1 = 0.f;
    for (int m = tid; m < kM; m += 256)
      s1 += sqrtf(fmaxf(__uint_as_float(ws[OFF_D1 + bs * kM + m]), 1e-12f));
    float s2 = 0.f;
    for (int i = tid; i < cnt; i += 256)
      s2 += sqrtf(fmaxf(__uint_as_float(ws[OFF_DM + off + i]), 1e-12f));
    for (int o = 32; o > 0; o >>= 1) {
      s1 += __shfl_down(s1, o);
      s2 += __shfl_down(s2, o);
    }
    if (lane == 0) { r1[wid] = s1; r2[wid] = s2; }
    __syncthreads();
    if (tid == 0) {
      const float a1 = r1[0] + r1[1] + r1[2] + r1[3];
      const float a2 = r2[0] + r2[1] + r2[2] + r2[3];
      const float d1 = a1 / (float)kM;
      const float d2m = a2 / (float)max(cnt, 1);
      cham[bs] = cnt > 0 ? 0.5f * (d1 + d2m) : 0.f;
      pres[bs] = cnt > 0 ? 1 : 0;
    }
    __syncthreads();
  }
  if (tid == 0) {
    float acc = 0.f;
    for (int b = 0; b < kB; ++b) {
      float sum = 0.f;
      int p = 0;
      for (int s = 0; s < kS; ++s) { sum += cham[b * kS + s]; p += pres[b * kS + s]; }
      acc += sum / (float)max(p, 1);
    }
    out[0] = acc / (float)kB;
  }
}

}  // namespace

extern "C" void kernel_launch(void* const* d_in, const int* in_sizes, int n_in,
                              void* d_out, int out_size, void* d_ws, size_t ws_size,
                              hipStream_t stream) {
  const float* ret = (const float*)d_in[0];    // (B, S*M*3) f32
  const float4* gt = (const float4*)d_in[1];   // (B, N, 4) f32
  const float* gtf = (const float*)d_in[1];
  unsigned int* ws = (unsigned int*)d_ws;

  kprep<<<INIT_BLOCKS + NCB, 256, 0, stream>>>(gtf, ws);
  koffsets<<<1, 64, 0, stream>>>(ws);
  kscatter<<<(kB * kN) / 256, 256, 0, stream>>>(gt, ws);
  kdist<<<K1_BLOCKS + K2_BLOCKS, 256, 0, stream>>>(ret, ws);
  kfinal<<<1, 256, 0, stream>>>(ws, (float*)d_out);
}

// Round 3
// 61.082 us; speedup vs baseline: 2.3824x; 2.0386x over previous
//
#include <hip/hip_runtime.h>
#include <math.h>

namespace {

constexpr int kB = 4;
constexpr int kS = 4;
constexpr int kM = 1024;
constexpr int kN = 8192;
constexpr int kBS = kB * kS;
constexpr float kBig2 = 1e20f;  // sqrt(1e20) = 1e10 == reference BIG

// ---- workspace layout (4-byte units) ----
constexpr int OFF_D1 = 0;                       // B*S*M  per-(b,s,m) min d2 bits
constexpr int OFF_DM = OFF_D1 + kBS * kM;       // B*N    per-compacted-gt min d2 bits
constexpr int OFF_CX = OFF_DM + kB * kN;        // B*N floats (compacted SoA)
constexpr int OFF_CY = OFF_CX + kB * kN;
constexpr int OFF_CZ = OFF_CY + kB * kN;
constexpr int NCB = (kB * kN) / 256;            // 128 count blocks
constexpr int OFF_BH = OFF_CZ + kB * kN;        // block histograms NCB*kS
constexpr int OFF_CNT = OFF_BH + NCB * kS;      // 16 counts
constexpr int OFF_OFS = OFF_CNT + kBS;          // 16 absolute bucket offsets
constexpr int OFF_CUR = OFF_OFS + kBS;          // 16 scatter cursors
constexpr int OFF_CHAM = OFF_CUR + kBS;         // 16 chamfer floats

constexpr int INIT_BLOCKS = (kBS * kM + kB * kN) / 256;  // 192 (d1 + dm contiguous)

constexpr int NSPL1 = 16;      // k1-role: split of bucket tiles
constexpr int K1_TILE = 128;
constexpr int K1_BLOCKS = kBS * NSPL1;          // 256
constexpr int GSPL = 4;        // k2-role: split over bucket points
constexpr int MSPL = 8;        // k2-role: split over M (tiles of 128)
constexpr int K2_BLOCKS = kBS * GSPL * MSPL;    // 512

// init d1/dm mins to BIG2 bits; per-block label histograms (no pre-zero needed).
__global__ __launch_bounds__(256) void kprep(const float* __restrict__ gtf,
                                             unsigned int* __restrict__ ws) {
  const int blk = blockIdx.x, tid = threadIdx.x;
  if (blk < INIT_BLOCKS) {
    ws[blk * 256 + tid] = __float_as_uint(kBig2);
  } else {
    const int cb = blk - INIT_BLOCKS;          // 256 points per block, single b
    const int idx = cb * 256 + tid;
    const int s = (int)gtf[idx * 4 + 3];
    __shared__ int h[kS];
    if (tid < kS) h[tid] = 0;
    __syncthreads();
    atomicAdd(&h[s], 1);
    __syncthreads();
    if (tid < kS) ((int*)ws)[OFF_BH + cb * kS + tid] = h[tid];
  }
}

// sum histograms -> counts; exclusive prefix per b -> offsets (+cursor copy).
__global__ void koffsets(unsigned int* ws) {
  const int t = threadIdx.x;  // 64 threads
  __shared__ int c[kBS];
  int* wi = (int*)ws;
  if (t < kBS) {
    const int b = t / kS, s = t % kS;
    int sum = 0;
    for (int j = 0; j < NCB / kB; ++j) sum += wi[OFF_BH + (b * (NCB / kB) + j) * kS + s];
    c[t] = sum;
    wi[OFF_CNT + t] = sum;
  }
  __syncthreads();
  if (t < kB) {
    int base = t * kN;
    for (int s = 0; s < kS; ++s) {
      wi[OFF_OFS + t * kS + s] = base;
      wi[OFF_CUR + t * kS + s] = base;
      base += c[t * kS + s];
    }
  }
}

// scatter gt into per-(b,s) buckets (SoA) with wave-aggregated cursor allocs.
__global__ __launch_bounds__(256) void kscatter(const float4* __restrict__ gt,
                                                unsigned int* __restrict__ ws) {
  const int idx = blockIdx.x * 256 + threadIdx.x;  // single b per block
  const int b = idx >> 13;
  const int lane = threadIdx.x & 63;
  const float4 q = gt[idx];
  const int s = (int)q.w;
  int* wi = (int*)ws;
  int pos = 0;
  for (int ss = 0; ss < kS; ++ss) {
    unsigned long long m = __ballot(s == ss);
    if (m != 0ull) {
      const int leader = __ffsll((unsigned long long)m) - 1;
      int base = 0;
      if (lane == leader) base = atomicAdd(&wi[OFF_CUR + b * kS + ss], (int)__popcll(m));
      base = __shfl(base, leader);
      if (s == ss) pos = base + (int)__popcll(m & ((1ull << lane) - 1ull));
    }
  }
  float* cx = (float*)(ws + OFF_CX);
  float* cy = (float*)(ws + OFF_CY);
  float* cz = (float*)(ws + OFF_CZ);
  cx[pos] = q.x;
  cy[pos] = q.y;
  cz[pos] = q.z;
}

// merged distance kernel: blocks [0,K1_BLOCKS) do pred->gt row mins,
// blocks [K1_BLOCKS, +K2_BLOCKS) do gt->pred col mins. All per-(b,s) bucket.
__global__ __launch_bounds__(256) void kdist(const float* __restrict__ ret,
                                             unsigned int* __restrict__ ws) {
  const int tid = threadIdx.x;
  __shared__ float4 tile4[K1_TILE];
  const int* wi = (const int*)ws;
  const float* cx = (const float*)(ws + OFF_CX);
  const float* cy = (const float*)(ws + OFF_CY);
  const float* cz = (const float*)(ws + OFF_CZ);

  if (blockIdx.x < K1_BLOCKS) {
    // ---- k1 role: 256 threads x 4 pred points = full M; loop bucket tiles ----
    const int nsp = blockIdx.x % NSPL1;
    const int bs = blockIdx.x / NSPL1;
    const int off = wi[OFF_OFS + bs];
    const int cnt = wi[OFF_CNT + bs];
    const float* p = ret + (bs * kM + tid) * 3;
    const float px0 = p[0], py0 = p[1], pz0 = p[2];
    const float px1 = p[768], py1 = p[769], pz1 = p[770];
    const float px2 = p[1536], py2 = p[1537], pz2 = p[1538];
    const float px3 = p[2304], py3 = p[2305], pz3 = p[2306];
    float b0 = kBig2, b1 = kBig2, b2 = kBig2, b3 = kBig2;
    for (int t = nsp; t * K1_TILE < cnt; t += NSPL1) {
      const int start = t * K1_TILE;
      __syncthreads();
      if (tid < K1_TILE) {
        const int j = start + tid;
        float4 v;
        if (j < cnt) { v.x = cx[off + j]; v.y = cy[off + j]; v.z = cz[off + j]; }
        else { v.x = 1e15f; v.y = 1e15f; v.z = 1e15f; }  // pad: never wins the min
        v.w = 0.f;
        tile4[tid] = v;
      }
      __syncthreads();
#pragma unroll 8
      for (int j = 0; j < K1_TILE; ++j) {
        const float4 tv = tile4[j];  // wave-uniform -> LDS broadcast
        float dx, dy, dz;
        dx = px0 - tv.x; dy = py0 - tv.y; dz = pz0 - tv.z;
        b0 = fminf(b0, fmaf(dx, dx, fmaf(dy, dy, dz * dz)));
        dx = px1 - tv.x; dy = py1 - tv.y; dz = pz1 - tv.z;
        b1 = fminf(b1, fmaf(dx, dx, fmaf(dy, dy, dz * dz)));
        dx = px2 - tv.x; dy = py2 - tv.y; dz = pz2 - tv.z;
        b2 = fminf(b2, fmaf(dx, dx, fmaf(dy, dy, dz * dz)));
        dx = px3 - tv.x; dy = py3 - tv.y; dz = pz3 - tv.z;
        b3 = fminf(b3, fmaf(dx, dx, fmaf(dy, dy, dz * dz)));
      }
    }
    atomicMin(&ws[OFF_D1 + bs * kM + tid], __float_as_uint(b0));
    atomicMin(&ws[OFF_D1 + bs * kM + tid + 256], __float_as_uint(b1));
    atomicMin(&ws[OFF_D1 + bs * kM + tid + 512], __float_as_uint(b2));
    atomicMin(&ws[OFF_D1 + bs * kM + tid + 768], __float_as_uint(b3));
  } else {
    // ---- k2 role: 256 threads x 2 gt points; loop 128-pred LDS tile ----
    int blk2 = blockIdx.x - K1_BLOCKS;
    const int ms = blk2 & (MSPL - 1); blk2 >>= 3;
    const int gs = blk2 & (GSPL - 1); blk2 >>= 2;
    const int bs = blk2;
    const int off = wi[OFF_OFS + bs];
    const int cnt = wi[OFF_CNT + bs];
    if (tid < 128) {
      const float* bp = ret + (bs * kM + ms * 128 + tid) * 3;
      tile4[tid] = make_float4(bp[0], bp[1], bp[2], 0.f);
    }
    __syncthreads();
    for (int base0 = gs * 512; base0 < cnt; base0 += GSPL * 512) {
      const int l0 = base0 + tid, l1 = base0 + 256 + tid;
      const bool v0 = l0 < cnt, v1 = l1 < cnt;
      const float gx0 = v0 ? cx[off + l0] : 0.f;
      const float gy0 = v0 ? cy[off + l0] : 0.f;
      const float gz0 = v0 ? cz[off + l0] : 0.f;
      const float gx1 = v1 ? cx[off + l1] : 0.f;
      const float gy1 = v1 ? cy[off + l1] : 0.f;
      const float gz1 = v1 ? cz[off + l1] : 0.f;
      float b0 = kBig2, b1 = kBig2;
#pragma unroll 8
      for (int mm = 0; mm < 128; ++mm) {
        const float4 pv = tile4[mm];  // wave-uniform broadcast
        float dx, dy, dz;
        dx = gx0 - pv.x; dy = gy0 - pv.y; dz = gz0 - pv.z;
        b0 = fminf(b0, fmaf(dx, dx, fmaf(dy, dy, dz * dz)));
        dx = gx1 - pv.x; dy = gy1 - pv.y; dz = gz1 - pv.z;
        b1 = fminf(b1, fmaf(dx, dx, fmaf(dy, dy, dz * dz)));
      }
      if (v0) atomicMin(&ws[OFF_DM + off + l0], __float_as_uint(b0));
      if (v1) atomicMin(&ws[OFF_DM + off + l1], __float_as_uint(b1));
    }
  }
}

// parallel epilogue stage 1: one block per (b,s) -> chamfer value in ws.
__global__ __launch_bounds__(256) void kreduce(unsigned int* __restrict__ ws) {
  const int tid = threadIdx.x, lane = tid & 63, wid = tid >> 6;
  const int bs = blockIdx.x;
  const int* wi = (const int*)ws;
  const int cnt = wi[OFF_CNT + bs];
  const int off = wi[OFF_OFS + bs];
  float s1 = 0.f;
#pragma unroll
  for (int m = tid; m < kM; m += 256)
    s1 += sqrtf(fmaxf(__uint_as_float(ws[OFF_D1 + bs * kM + m]), 1e-12f));
  float s2 = 0.f;
  for (int i = tid; i < cnt; i += 256)
    s2 += sqrtf(fmaxf(__uint_as_float(ws[OFF_DM + off + i]), 1e-12f));
  for (int o = 32; o > 0; o >>= 1) {
    s1 += __shfl_down(s1, o);
    s2 += __shfl_down(s2, o);
  }
  __shared__ float r1[4], r2[4];
  if (lane == 0) { r1[wid] = s1; r2[wid] = s2; }
  __syncthreads();
  if (tid == 0) {
    const float a1 = r1[0] + r1[1] + r1[2] + r1[3];
    const float a2 = r2[0] + r2[1] + r2[2] + r2[3];
    const float d1 = a1 / (float)kM;
    const float d2m = a2 / (float)max(cnt, 1);
    ((float*)ws)[OFF_CHAM + bs] = cnt > 0 ? 0.5f * (d1 + d2m) : 0.f;
  }
}

// parallel epilogue stage 2: combine the 16 (b,s) chamfer values.
__global__ void kfinal2(const unsigned int* __restrict__ ws,
                        float* __restrict__ out) {
  const int t = threadIdx.x;  // 64 threads
  const int* wi = (const int*)ws;
  float ch = 0.f;
  int pr = 0;
  if (t < kBS) {
    ch = ((const float*)ws)[OFF_CHAM + t];
    pr = wi[OFF_CNT + t] > 0 ? 1 : 0;
  }
  // lanes 0..15 hold (b = t/4, s = t%4); reduce s within each 4-lane group
  for (int o = 1; o < 4; o <<= 1) {
    ch += __shfl_down(ch, o);
    pr += __shfl_down(pr, o);
  }
  if ((t & 3) == 0 && t < kBS) {
    float v = ch / (float)max(pr, 1);  // per-sample
    // lanes 0,4,8,12 -> sum across b then /kB
    float acc = v;
    acc += __shfl_down(acc, 4);
    acc += __shfl_down(acc, 8);
    if (t == 0) out[0] = acc / (float)kB;
  }
}

}  // namespace

extern "C" void kernel_launch(void* const* d_in, const int* in_sizes, int n_in,
                              void* d_out, int out_size, void* d_ws, size_t ws_size,
                              hipStream_t stream) {
  const float* ret = (const float*)d_in[0];    // (B, S*M*3) f32
  const float4* gt = (const float4*)d_in[1];   // (B, N, 4) f32
  const float* gtf = (const float*)d_in[1];
  unsigned int* ws = (unsigned int*)d_ws;

  kprep<<<INIT_BLOCKS + NCB, 256, 0, stream>>>(gtf, ws);
  koffsets<<<1, 64, 0, stream>>>(ws);
  kscatter<<<(kB * kN) / 256, 256, 0, stream>>>(gt, ws);
  kdist<<<K1_BLOCKS + K2_BLOCKS, 256, 0, stream>>>(ret, ws);
  kreduce<<<kBS, 256, 0, stream>>>(ws);
  kfinal2<<<1, 64, 0, stream>>>(ws, (float*)d_out);
}

// Round 4
// 55.063 us; speedup vs baseline: 2.6428x; 1.1093x over previous
//
#include <hip/hip_runtime.h>
#include <math.h>

namespace {

constexpr int kB = 4;
constexpr int kS = 4;
constexpr int kM = 1024;
constexpr int kN = 8192;
constexpr int kBS = kB * kS;
constexpr float kBig2 = 1e20f;  // sqrt(1e20) = 1e10 == reference BIG

// ---- workspace layout (4-byte words) ----
constexpr int OFF_D1 = 0;                        // kBS*kM min-d2 bits
constexpr int OFF_DM = OFF_D1 + kBS * kM;        // kBS*kN min-d2 bits (fixed regions)
constexpr int OFF_C4 = OFF_DM + kBS * kN;        // float4[kBS*kN] gt buckets {x,y,z,|g|^2}
constexpr int OFF_P4 = OFF_C4 + 4 * kBS * kN;    // float4[kBS*kM] preds {x,y,z,|p|^2}
constexpr int OFF_CUR = OFF_P4 + 4 * kBS * kM;   // 16 scatter cursors

constexpr int INIT_WORDS = kBS * kM + kBS * kN;  // 147456 (D1+DM contiguous)
constexpr int INIT_BLOCKS = INIT_WORDS / 256;    // 576
constexpr int P4_BLOCKS = kBS * kM / 256;        // 64

constexpr int NSPL1 = 16;                        // K1: gt split, tiles of 128
constexpr int K1_TILE = 128;
constexpr int K1_BLOCKS = kBS * NSPL1;           // 256
constexpr int GSPL = 2;                          // K2: gt chunks of 1024 (4/thread)
constexpr int MSPL = 8;                          // K2: pred tiles of 128
constexpr int K2_BLOCKS = kBS * GSPL * MSPL;     // 256

// init mins to BIG2 bits, cursors to bucket bases, out to 0, build pred4.
__global__ __launch_bounds__(256) void kprep(const float* __restrict__ ret,
                                             unsigned int* __restrict__ ws,
                                             float* __restrict__ out) {
  const int blk = blockIdx.x, tid = threadIdx.x;
  if (blk < INIT_BLOCKS) {
    ws[blk * 256 + tid] = __float_as_uint(kBig2);
    return;
  }
  if (blk == INIT_BLOCKS) {
    if (tid < kBS) ((int*)ws)[OFF_CUR + tid] = tid * kN;
    if (tid == kBS) out[0] = 0.f;
    return;
  }
  const int gi = (blk - INIT_BLOCKS - 1) * 256 + tid;  // 0..16383
  const float x = ret[gi * 3], y = ret[gi * 3 + 1], z = ret[gi * 3 + 2];
  ((float4*)(ws + OFF_P4))[gi] = make_float4(x, y, z, fmaf(x, x, fmaf(y, y, z * z)));
}

// scatter gt into fixed per-(b,s) regions, wave-aggregated cursor allocs.
__global__ __launch_bounds__(256) void kscatter(const float4* __restrict__ gt,
                                                unsigned int* __restrict__ ws) {
  const int idx = blockIdx.x * 256 + threadIdx.x;  // single b per block
  const int b = idx >> 13;
  const int lane = threadIdx.x & 63;
  const float4 q = gt[idx];
  const int s = (int)q.w;
  int* cur = (int*)ws + OFF_CUR;
  int pos = 0;
  for (int ss = 0; ss < kS; ++ss) {
    unsigned long long m = __ballot(s == ss);
    if (m != 0ull) {
      const int leader = __ffsll((unsigned long long)m) - 1;
      int base = 0;
      if (lane == leader) base = atomicAdd(&cur[b * kS + ss], (int)__popcll(m));
      base = __shfl(base, leader);
      if (s == ss) pos = base + (int)__popcll(m & ((1ull << lane) - 1ull));
    }
  }
  const float gn = fmaf(q.x, q.x, fmaf(q.y, q.y, q.z * q.z));
  ((float4*)(ws + OFF_C4))[pos] = make_float4(q.x, q.y, q.z, gn);
}

// merged distance kernel, dot-expansion form: per pair 3 FMA + 1 min.
// K1 blocks: per (b,s,m) min over bucket. K2 blocks: per gt point min over M.
__global__ __launch_bounds__(256) void kdist(unsigned int* __restrict__ ws) {
  const int tid = threadIdx.x;
  __shared__ float4 tile[K1_TILE];
  const int* cur = (const int*)ws + OFF_CUR;
  const float4* c4 = (const float4*)(ws + OFF_C4);
  const float4* p4 = (const float4*)(ws + OFF_P4);

  if (blockIdx.x < K1_BLOCKS) {
    const int t = blockIdx.x & (NSPL1 - 1);
    const int bs = blockIdx.x >> 4;
    const int cnt = cur[bs] - bs * kN;
    const float4 P0 = p4[bs * kM + tid];
    const float4 P1 = p4[bs * kM + tid + 256];
    const float4 P2 = p4[bs * kM + tid + 512];
    const float4 P3 = p4[bs * kM + tid + 768];
    const float ax0 = -2.f * P0.x, ay0 = -2.f * P0.y, az0 = -2.f * P0.z;
    const float ax1 = -2.f * P1.x, ay1 = -2.f * P1.y, az1 = -2.f * P1.z;
    const float ax2 = -2.f * P2.x, ay2 = -2.f * P2.y, az2 = -2.f * P2.z;
    const float ax3 = -2.f * P3.x, ay3 = -2.f * P3.y, az3 = -2.f * P3.z;
    float b0 = kBig2, b1 = kBig2, b2 = kBig2, b3 = kBig2;
    for (int start = t * K1_TILE; start < cnt; start += NSPL1 * K1_TILE) {
      __syncthreads();
      if (tid < K1_TILE) {
        const int j = start + tid;
        // pad (0,0,0,BIG2): t = BIG2, never wins the min
        tile[tid] = (j < cnt) ? c4[bs * kN + j] : make_float4(0.f, 0.f, 0.f, kBig2);
      }
      __syncthreads();
#pragma unroll 8
      for (int j = 0; j < K1_TILE; ++j) {
        const float4 g = tile[j];  // wave-uniform -> LDS broadcast
        b0 = fminf(b0, fmaf(ax0, g.x, fmaf(ay0, g.y, fmaf(az0, g.z, g.w))));
        b1 = fminf(b1, fmaf(ax1, g.x, fmaf(ay1, g.y, fmaf(az1, g.z, g.w))));
        b2 = fminf(b2, fmaf(ax2, g.x, fmaf(ay2, g.y, fmaf(az2, g.z, g.w))));
        b3 = fminf(b3, fmaf(ax3, g.x, fmaf(ay3, g.y, fmaf(az3, g.z, g.w))));
      }
    }
    // +|p|^2 outside the min; clamp: negative bits would lose the uint-min.
    atomicMin(&ws[OFF_D1 + bs * kM + tid],       __float_as_uint(fmaxf(b0 + P0.w, 0.f)));
    atomicMin(&ws[OFF_D1 + bs * kM + tid + 256], __float_as_uint(fmaxf(b1 + P1.w, 0.f)));
    atomicMin(&ws[OFF_D1 + bs * kM + tid + 512], __float_as_uint(fmaxf(b2 + P2.w, 0.f)));
    atomicMin(&ws[OFF_D1 + bs * kM + tid + 768], __float_as_uint(fmaxf(b3 + P3.w, 0.f)));
  } else {
    int r = blockIdx.x - K1_BLOCKS;
    const int ms = r & (MSPL - 1); r >>= 3;
    const int gs = r & (GSPL - 1); r >>= 1;
    const int bs = r;
    const int cnt = cur[bs] - bs * kN;
    if (tid < K1_TILE) tile[tid] = p4[bs * kM + ms * K1_TILE + tid];
    __syncthreads();
    for (int base = gs * 1024; base < cnt; base += GSPL * 1024) {
      const int l0 = base + tid, l1 = l0 + 256, l2 = l0 + 512, l3 = l0 + 768;
      const bool v0 = l0 < cnt, v1 = l1 < cnt, v2 = l2 < cnt, v3 = l3 < cnt;
      const float4 G0 = v0 ? c4[bs * kN + l0] : make_float4(0.f, 0.f, 0.f, 0.f);
      const float4 G1 = v1 ? c4[bs * kN + l1] : make_float4(0.f, 0.f, 0.f, 0.f);
      const float4 G2 = v2 ? c4[bs * kN + l2] : make_float4(0.f, 0.f, 0.f, 0.f);
      const float4 G3 = v3 ? c4[bs * kN + l3] : make_float4(0.f, 0.f, 0.f, 0.f);
      const float ax0 = -2.f * G0.x, ay0 = -2.f * G0.y, az0 = -2.f * G0.z;
      const float ax1 = -2.f * G1.x, ay1 = -2.f * G1.y, az1 = -2.f * G1.z;
      const float ax2 = -2.f * G2.x, ay2 = -2.f * G2.y, az2 = -2.f * G2.z;
      const float ax3 = -2.f * G3.x, ay3 = -2.f * G3.y, az3 = -2.f * G3.z;
      float b0 = kBig2, b1 = kBig2, b2 = kBig2, b3 = kBig2;
#pragma unroll 8
      for (int mm = 0; mm < K1_TILE; ++mm) {
        const float4 p = tile[mm];  // wave-uniform broadcast
        b0 = fminf(b0, fmaf(ax0, p.x, fmaf(ay0, p.y, fmaf(az0, p.z, p.w))));
        b1 = fminf(b1, fmaf(ax1, p.x, fmaf(ay1, p.y, fmaf(az1, p.z, p.w))));
        b2 = fminf(b2, fmaf(ax2, p.x, fmaf(ay2, p.y, fmaf(az2, p.z, p.w))));
        b3 = fminf(b3, fmaf(ax3, p.x, fmaf(ay3, p.y, fmaf(az3, p.z, p.w))));
      }
      if (v0) atomicMin(&ws[OFF_DM + bs * kN + l0], __float_as_uint(fmaxf(b0 + G0.w, 0.f)));
      if (v1) atomicMin(&ws[OFF_DM + bs * kN + l1], __float_as_uint(fmaxf(b1 + G1.w, 0.f)));
      if (v2) atomicMin(&ws[OFF_DM + bs * kN + l2], __float_as_uint(fmaxf(b2 + G2.w, 0.f)));
      if (v3) atomicMin(&ws[OFF_DM + bs * kN + l3], __float_as_uint(fmaxf(b3 + G3.w, 0.f)));
    }
  }
}

// fused epilogue: one block per (b,s); pres_b from cursors; atomicAdd into out.
__global__ __launch_bounds__(256) void krf(const unsigned int* __restrict__ ws,
                                           float* __restrict__ out) {
  const int tid = threadIdx.x, lane = tid & 63, wid = tid >> 6;
  const int bs = blockIdx.x, b = bs >> 2;
  const int* cur = (const int*)ws + OFF_CUR;
  const int cnt = cur[bs] - bs * kN;
  float s1 = 0.f;
  for (int m = tid; m < kM; m += 256)
    s1 += sqrtf(fmaxf(__uint_as_float(ws[OFF_D1 + bs * kM + m]), 1e-12f));
  float s2 = 0.f;
  for (int i = tid; i < cnt; i += 256)
    s2 += sqrtf(fmaxf(__uint_as_float(ws[OFF_DM + bs * kN + i]), 1e-12f));
  for (int o = 32; o > 0; o >>= 1) {
    s1 += __shfl_down(s1, o);
    s2 += __shfl_down(s2, o);
  }
  __shared__ float r1[4], r2[4];
  if (lane == 0) { r1[wid] = s1; r2[wid] = s2; }
  __syncthreads();
  if (tid == 0) {
    const float a1 = r1[0] + r1[1] + r1[2] + r1[3];
    const float a2 = r2[0] + r2[1] + r2[2] + r2[3];
    int pres = 0;
    for (int s = 0; s < kS; ++s) pres += (cur[b * kS + s] - (b * kS + s) * kN) > 0 ? 1 : 0;
    const float cham = cnt > 0 ? 0.5f * (a1 / (float)kM + a2 / (float)max(cnt, 1)) : 0.f;
    atomicAdd(out, cham / (float)(kB * max(pres, 1)));
  }
}

}  // namespace

extern "C" void kernel_launch(void* const* d_in, const int* in_sizes, int n_in,
                              void* d_out, int out_size, void* d_ws, size_t ws_size,
                              hipStream_t stream) {
  const float* ret = (const float*)d_in[0];    // (B, S*M*3) f32 == (BS, M, 3)
  const float4* gt = (const float4*)d_in[1];   // (B, N, 4) f32
  unsigned int* ws = (unsigned int*)d_ws;
  float* out = (float*)d_out;

  kprep<<<INIT_BLOCKS + 1 + P4_BLOCKS, 256, 0, stream>>>(ret, ws, out);
  kscatter<<<(kB * kN) / 256, 256, 0, stream>>>(gt, ws);
  kdist<<<K1_BLOCKS + K2_BLOCKS, 256, 0, stream>>>(ws);
  krf<<<kBS, 256, 0, stream>>>(ws, out);
}